// Round 1
// baseline (45.228 us; speedup 1.0000x reference)
//
#include <hip/hip_runtime.h>

#define B_ 4
#define R_ 48
#define VR_ 96

// Kernel 1: one block per (b, r, s). Gather 96+96 points to LDS, all-pairs
// min distance^2 via 6x6 register tiles, block min-reduce, sqrt once.
__global__ __launch_bounds__(256) void min_dist_kernel(
    const float* __restrict__ v1s, const float* __restrict__ v2s,
    const int* __restrict__ rid_to_vid, float* __restrict__ min_out, int N) {
  const int bid = blockIdx.x;              // b*R*R + r*R + s
  const int b  = bid / (R_ * R_);
  const int rs = bid % (R_ * R_);
  const int r  = rs / R_;
  const int s  = rs % R_;

  __shared__ float p1[VR_][3];
  __shared__ float p2[VR_][3];

  const int t = threadIdx.x;
  if (t < 2 * VR_) {
    const int which = (t >= VR_) ? 1 : 0;  // 0 -> g1 (row r of v1s), 1 -> g2 (row s of v2s)
    const int v = which ? (t - VR_) : t;
    const int row = which ? s : r;
    const int idx = rid_to_vid[row * VR_ + v];
    const float* src = (which ? v2s : v1s) + ((long)b * N + idx) * 3;
    const float x = src[0], y = src[1], z = src[2];
    if (which) { p2[v][0] = x; p2[v][1] = y; p2[v][2] = z; }
    else       { p1[v][0] = x; p1[v][1] = y; p1[v][2] = z; }
  }
  __syncthreads();

  // 16x16 thread grid of 6x6 (v,w) tiles covers 96x96 pairs.
  const int tv = (t >> 4) * 6;
  const int tw = (t & 15) * 6;
  float ax[6], ay[6], az[6], cx[6], cy[6], cz[6];
#pragma unroll
  for (int i = 0; i < 6; ++i) {
    ax[i] = p1[tv + i][0]; ay[i] = p1[tv + i][1]; az[i] = p1[tv + i][2];
    cx[i] = p2[tw + i][0]; cy[i] = p2[tw + i][1]; cz[i] = p2[tw + i][2];
  }

  float mind2 = 3.4e38f;
#pragma unroll
  for (int i = 0; i < 6; ++i) {
#pragma unroll
    for (int j = 0; j < 6; ++j) {
      const float dx = ax[i] - cx[j];
      const float dy = ay[i] - cy[j];
      const float dz = az[i] - cz[j];
      const float d2 = dx * dx + dy * dy + dz * dz;
      mind2 = fminf(mind2, d2);
    }
  }

  // block min-reduction: wave shuffle (64 lanes) then cross-wave via LDS
#pragma unroll
  for (int off = 32; off > 0; off >>= 1)
    mind2 = fminf(mind2, __shfl_down(mind2, off, 64));
  __shared__ float wmin[4];
  if ((t & 63) == 0) wmin[t >> 6] = mind2;
  __syncthreads();
  if (t == 0) {
    const float m = fminf(fminf(wmin[0], wmin[1]), fminf(wmin[2], wmin[3]));
    min_out[bid] = sqrtf(fmaxf(m, 0.0f));  // sqrt(min(d2)) == min(sqrt(d2))
  }
}

// Kernel 2: masked mean over (r,s) per batch. Detects cmaps storage layout
// (1-byte bool vs 4-byte int32/f32) from byte patterns — deterministic for
// fixed inputs.
__global__ __launch_bounds__(256) void finalize_kernel(
    const float* __restrict__ min_d, const unsigned char* __restrict__ cm,
    float* __restrict__ out) {
  const int b = blockIdx.x;
  const int t = threadIdx.x;

  __shared__ int stride4_s;
  if (t == 0) {
    // Scan first 256 bytes (safe: cmaps has >= 9216 bytes in any layout).
    // int32 layout: bytes at i%4!=0 are all 0 (values are 0/1).
    // f32  layout: bytes at i%4!=0 include 0x80/0x3F (exponent of 1.0f).
    // bool layout: bytes at i%4!=0 are random 0/1 (some nonzero, none >1).
    bool nz = false, big = false;
    for (int i = 1; i < 256; ++i) {
      if (i & 3) {
        const unsigned char v = cm[i];
        if (v) { nz = true; if (v > 1) big = true; }
      }
    }
    stride4_s = (big || !nz) ? 1 : 0;  // 4-byte elements if int32 or f32
  }
  __syncthreads();
  const int stride4 = stride4_s;
  const unsigned int* cm32 = (const unsigned int*)cm;

  float sum = 0.0f, cnt = 0.0f;
  for (int i = t; i < R_ * R_; i += 256) {
    const int gi = b * R_ * R_ + i;
    const bool m = stride4 ? (cm32[gi] != 0u) : (cm[gi] != 0);
    if (m) { sum += min_d[gi]; cnt += 1.0f; }
  }
#pragma unroll
  for (int off = 32; off > 0; off >>= 1) {
    sum += __shfl_down(sum, off, 64);
    cnt += __shfl_down(cnt, off, 64);
  }
  __shared__ float ws_[4], wc_[4];
  if ((t & 63) == 0) { ws_[t >> 6] = sum; wc_[t >> 6] = cnt; }
  __syncthreads();
  if (t == 0) {
    const float S = ws_[0] + ws_[1] + ws_[2] + ws_[3];
    const float C = wc_[0] + wc_[1] + wc_[2] + wc_[3];
    out[b] = S / C;
  }
}

extern "C" void kernel_launch(void* const* d_in, const int* in_sizes, int n_in,
                              void* d_out, int out_size, void* d_ws, size_t ws_size,
                              hipStream_t stream) {
  const float* v1s = (const float*)d_in[0];
  const float* v2s = (const float*)d_in[1];
  const unsigned char* cmaps = (const unsigned char*)d_in[2];
  const int* rid_to_vid = (const int*)d_in[3];
  float* out = (float*)d_out;
  float* minbuf = (float*)d_ws;  // B*R*R floats = 36 KB

  const int N = in_sizes[0] / (B_ * 3);

  min_dist_kernel<<<B_ * R_ * R_, 256, 0, stream>>>(v1s, v2s, rid_to_vid, minbuf, N);
  finalize_kernel<<<B_, 256, 0, stream>>>(minbuf, cmaps, out);
}

// Round 2
// 26.993 us; speedup vs baseline: 1.6756x; 1.6756x over previous
//
#include <hip/hip_runtime.h>

#define B_ 4
#define R_ 48
#define VR_ 96
#define NROWS (B_ * 2 * R_)        // 384 gathered rows (g1 and g2 per (b,r))
#define ROWF 288                   // floats per row: SoA x[96] y[96] z[96]

// ---------------------------------------------------------------------------
// Kernel 0: compact gather. One thread per (b,set,r,v) point. Writes SoA rows
// so the main kernel's LDS staging is a linear float4 copy.
__global__ __launch_bounds__(256) void gather_kernel(
    const float* __restrict__ v1s, const float* __restrict__ v2s,
    const int* __restrict__ rid_to_vid, float* __restrict__ gbuf, int N) {
  const int i = blockIdx.x * 256 + threadIdx.x;
  if (i >= NROWS * VR_) return;
  const int v = i % VR_;
  const int row = i / VR_;           // (b*2+set)*48 + r
  const int r = row % R_;
  const int bs = row / R_;
  const int set = bs & 1;
  const int b = bs >> 1;
  const int idx = rid_to_vid[r * VR_ + v];
  const float* src = (set ? v2s : v1s) + ((size_t)b * N + idx) * 3;
  float* dst = gbuf + (size_t)row * ROWF;
  dst[v] = src[0];
  dst[VR_ + v] = src[1];
  dst[2 * VR_ + v] = src[2];
}

// ---------------------------------------------------------------------------
// Kernel 1: one WAVE per (b,r,s) cell; 4 cells per block share the g1 row.
// grid = B*R*(R/4) = 2304 blocks. Lane (hi,lo) in 8x8 grid owns a 12x12 pair
// tile. SoA LDS: reads hit 8 distinct banks, 8-lane broadcast -> conflict-free.
__global__ __launch_bounds__(256) void cell_kernel(
    const float* __restrict__ gbuf, float* __restrict__ minbuf) {
  const int bid = blockIdx.x;                 // b*(48*12) + r*12 + quad
  const int b = bid / (R_ * 12);
  const int rem = bid % (R_ * 12);
  const int r = rem / 12;
  const int quad = rem % 12;

  __shared__ float s1[ROWF];
  __shared__ float s2[4 * ROWF];

  const float* g1 = gbuf + (size_t)((b * 2 + 0) * R_ + r) * ROWF;
  const float* g2 = gbuf + (size_t)((b * 2 + 1) * R_ + quad * 4) * ROWF;  // 4 contiguous rows

  const int t = threadIdx.x;
  // linear float4 staging: 72 f4 for s1, 288 f4 for s2
  const float4* g1v = (const float4*)g1;
  const float4* g2v = (const float4*)g2;
  float4* s1v = (float4*)s1;
  float4* s2v = (float4*)s2;
  if (t < 72) s1v[t] = g1v[t];
  s2v[t] = g2v[t];
  if (t < 32) s2v[256 + t] = g2v[256 + t];
  __syncthreads();

  const int w = t >> 6;          // wave -> cell s = quad*4 + w
  const int lane = t & 63;
  const float* r2 = s2 + w * ROWF;
  const int hi = lane >> 3;      // g1 group: points hi*12 .. hi*12+11
  const int lo = lane & 7;       // g2 group: points lo*12 .. lo*12+11

  float ax[12], ay[12], az[12];
#pragma unroll
  for (int i = 0; i < 12; ++i) {
    const int vi = hi * 12 + i;
    ax[i] = s1[vi]; ay[i] = s1[VR_ + vi]; az[i] = s1[2 * VR_ + vi];
  }

  float acc[4] = {3.4e38f, 3.4e38f, 3.4e38f, 3.4e38f};
#pragma unroll
  for (int j = 0; j < 12; ++j) {
    const int wj = lo * 12 + j;
    const float bx = r2[wj], by = r2[VR_ + wj], bz = r2[2 * VR_ + wj];
#pragma unroll
    for (int i = 0; i < 12; ++i) {
      const float dx = ax[i] - bx;
      const float dy = ay[i] - by;
      const float dz = az[i] - bz;
      const float d2 = dx * dx + dy * dy + dz * dz;
      acc[i & 3] = fminf(acc[i & 3], d2);   // i is compile-time (unrolled)
    }
  }
  float mind2 = fminf(fminf(acc[0], acc[1]), fminf(acc[2], acc[3]));
#pragma unroll
  for (int off = 32; off > 0; off >>= 1)
    mind2 = fminf(mind2, __shfl_down(mind2, off, 64));
  if (lane == 0)
    minbuf[(b * R_ + r) * R_ + quad * 4 + w] = sqrtf(fmaxf(mind2, 0.0f));
}

// ---------------------------------------------------------------------------
// Kernel 2: masked mean per batch. Wave-parallel detection of cmaps layout
// (1-byte bool vs 4-byte int32/f32) — deterministic for fixed inputs.
__global__ __launch_bounds__(256) void finalize_kernel(
    const float* __restrict__ min_d, const unsigned char* __restrict__ cm,
    float* __restrict__ out) {
  const int b = blockIdx.x;
  const int t = threadIdx.x;
  const unsigned int* cm32 = (const unsigned int*)cm;

  __shared__ int stride4_s;
  if (t < 64) {
    // 64 lanes x 1 dword covers first 256 bytes. Check bytes 1..3 of each
    // dword: int32 layout -> all zero; f32 layout -> contains 0x80/0x3F;
    // bool layout -> random 0/1 bytes (some nonzero, none > 1).
    const unsigned int d = cm32[t];
    const unsigned int b1 = (d >> 8) & 0xff, b2 = (d >> 16) & 0xff, b3 = d >> 24;
    const bool nz = (b1 | b2 | b3) != 0;
    const bool big = (b1 > 1) || (b2 > 1) || (b3 > 1);
    const unsigned long long nzm = __ballot(nz);
    const unsigned long long bigm = __ballot(big);
    if (t == 0) stride4_s = (bigm != 0ull || nzm == 0ull) ? 1 : 0;
  }
  __syncthreads();
  const int stride4 = stride4_s;

  float sum = 0.0f, cnt = 0.0f;
  for (int i = t; i < R_ * R_; i += 256) {
    const int gi = b * R_ * R_ + i;
    const bool m = stride4 ? (cm32[gi] != 0u) : (cm[gi] != 0);
    if (m) { sum += min_d[gi]; cnt += 1.0f; }
  }
#pragma unroll
  for (int off = 32; off > 0; off >>= 1) {
    sum += __shfl_down(sum, off, 64);
    cnt += __shfl_down(cnt, off, 64);
  }
  __shared__ float ws_[4], wc_[4];
  if ((t & 63) == 0) { ws_[t >> 6] = sum; wc_[t >> 6] = cnt; }
  __syncthreads();
  if (t == 0) {
    const float S = ws_[0] + ws_[1] + ws_[2] + ws_[3];
    const float C = wc_[0] + wc_[1] + wc_[2] + wc_[3];
    out[b] = S / C;
  }
}

// ---------------------------------------------------------------------------
extern "C" void kernel_launch(void* const* d_in, const int* in_sizes, int n_in,
                              void* d_out, int out_size, void* d_ws, size_t ws_size,
                              hipStream_t stream) {
  const float* v1s = (const float*)d_in[0];
  const float* v2s = (const float*)d_in[1];
  const unsigned char* cmaps = (const unsigned char*)d_in[2];
  const int* rid_to_vid = (const int*)d_in[3];
  float* out = (float*)d_out;

  float* minbuf = (float*)d_ws;                       // 9216 floats = 36 KB
  float* gbuf = (float*)((char*)d_ws + (64 << 10));   // 384*288 floats = 442 KB

  const int N = in_sizes[0] / (B_ * 3);

  gather_kernel<<<(NROWS * VR_ + 255) / 256, 256, 0, stream>>>(v1s, v2s, rid_to_vid, gbuf, N);
  cell_kernel<<<B_ * R_ * 12, 256, 0, stream>>>(gbuf, minbuf);
  finalize_kernel<<<B_, 256, 0, stream>>>(minbuf, cmaps, out);
}